// Round 11
// baseline (192.756 us; speedup 1.0000x reference)
//
#include <hip/hip_runtime.h>

// (B,P,C,H,W)=(256,10,32,8,8); Tm=19, Ta=10, hw=64. All I/O fp32.
// Horner: A_0=[F_0;1]; A_{p+1}=A_p*M_p+[F_{p+1};1] (p=0..8) -> A_9=[G;W]
// out[b,t,c,j] = (G[c,:].M_t[:,j]) / (W.M_t[:,j] + eps)
//
// v11 = v10 (2 half-blocks/batch, grid 512, 4 waves/SIMD, phase 1 in
// registers via v_readlane) + 32-deep double-buffered REGISTER chunks for M
// (~85 VGPR, under the (512,4) cap of 128 -- v9's 64-deep version needed
// ~140 and got sunk) + phase 2 split into 20 half-jobs (crit path 1.5 jobs).

#define EPSV 1e-6f

__device__ __forceinline__ float rdlane(float v, int k) {
    return __int_as_float(__builtin_amdgcn_readlane(__float_as_int(v), k));
}

__global__ __launch_bounds__(512, 4) void k_fused(
    const float* __restrict__ feats,   // (256,10,32,64)
    const float* __restrict__ sim,     // (256,19,64,64)
    float* __restrict__ out)           // (2560,32,64)
{
    // Gt[k*20 + r'], r'=0..15 half-G rows, r'=16 = W row. 5 KB.
    __shared__ __attribute__((aligned(16))) float Gt[1280];

    const int tid  = threadIdx.x;
    const int lane = tid & 63;
    const int wave = tid >> 6;          // 0..7
    const int b    = blockIdx.x >> 1;
    const int h    = blockIdx.x & 1;    // row-half of the batch

    const float* fb = feats + (size_t)b * 20480;   // 10*32*64
    const float* sb = sim   + (size_t)b * 77824;   // 19*64*64

    // ---- phase 1: wave owns rows r0,r0+1 (wave 7 also W). Registers only. ----
    const int r0 = 16 * h + 2 * wave;
    float a0 = fb[(r0 + 0) * 64 + lane];
    float a1 = fb[(r0 + 1) * 64 + lane];
    float aw = 1.0f;

    float mc[32], mn[32];               // M column chunks (static-index regs)
    #pragma unroll
    for (int k = 0; k < 32; ++k) mc[k] = sb[k * 64 + lane];   // M_0 lower half

    for (int p = 0; p < 9; ++p) {
        const float* __restrict__ Mp = sb + p * 4096;
        const float* __restrict__ F  = fb + (p + 1) * 2048;
        const float f0 = F[(r0 + 0) * 64 + lane];
        const float f1 = F[(r0 + 1) * 64 + lane];

        // prefetch upper chunk of M_p while computing on the lower chunk
        #pragma unroll
        for (int k = 0; k < 32; ++k) mn[k] = Mp[(32 + k) * 64 + lane];

        float c0 = 0.f, c1 = 0.f, cw = 0.f;
        if (wave == 7) {                // wave-uniform branch
            #pragma unroll
            for (int k = 0; k < 32; ++k) {
                const float m = mc[k];
                c0 += rdlane(a0, k) * m;
                c1 += rdlane(a1, k) * m;
                cw += rdlane(aw, k) * m;
            }
        } else {
            #pragma unroll
            for (int k = 0; k < 32; ++k) {
                const float m = mc[k];
                c0 += rdlane(a0, k) * m;
                c1 += rdlane(a1, k) * m;
            }
        }
        // prefetch lower chunk of M_{p+1} while computing on the upper chunk
        if (p < 8) {
            #pragma unroll
            for (int k = 0; k < 32; ++k) mc[k] = Mp[4096 + k * 64 + lane];
        }
        if (wave == 7) {
            #pragma unroll
            for (int k = 0; k < 32; ++k) {
                const float m = mn[k];
                c0 += rdlane(a0, 32 + k) * m;
                c1 += rdlane(a1, 32 + k) * m;
                cw += rdlane(aw, 32 + k) * m;
            }
        } else {
            #pragma unroll
            for (int k = 0; k < 32; ++k) {
                const float m = mn[k];
                c0 += rdlane(a0, 32 + k) * m;
                c1 += rdlane(a1, 32 + k) * m;
            }
        }
        a0 = c0 + f0; a1 = c1 + f1; aw = cw + 1.0f;
    }

    // ---- handoff: half G + W -> LDS (k = lane, one-time transposed writes) ----
    Gt[lane * 20 + 2 * wave + 0] = a0;
    Gt[lane * 20 + 2 * wave + 1] = a1;
    if (wave == 7) Gt[lane * 20 + 16] = aw;
    __syncthreads();                    // the kernel's only barrier

    // ---- phase 2: 20 half-jobs (t, 8-row half) over 8 waves; barrier-free ----
    const int rr = (lane >> 4) * 2;     // 0,2,4,6 within the 8-row half
    const int jj = (lane & 15) * 4;
    const int njobs = (wave < 4) ? 3 : 2;

    for (int rep = 0; rep < njobs; ++rep) {
        const int job = wave + 8 * rep;         // 0..19
        const int t   = job >> 1;
        const int rh  = (job & 1) * 8;          // row-half offset within our 16
        const float* __restrict__ Mt = sb + (9 + t) * 4096;

        float acc[8];
        #pragma unroll
        for (int i = 0; i < 8; ++i) acc[i] = 0.f;
        float wv0 = 0.f, wv1 = 0.f, wv2 = 0.f, wv3 = 0.f;

        #pragma unroll 16
        for (int k = 0; k < 64; ++k) {
            const float2 g  = *(const float2*)&Gt[k * 20 + rh + rr];  // 2 rows @ k
            const float  wk = Gt[k * 20 + 16];                        // W[k], broadcast
            const float4 m  = *(const float4*)&Mt[k * 64 + jj];       // global b128
            wv0 += wk * m.x; wv1 += wk * m.y; wv2 += wk * m.z; wv3 += wk * m.w;
            acc[0] += g.x*m.x; acc[1] += g.x*m.y; acc[2] += g.x*m.z; acc[3] += g.x*m.w;
            acc[4] += g.y*m.x; acc[5] += g.y*m.y; acc[6] += g.y*m.z; acc[7] += g.y*m.w;
        }

        float4 rw;
        rw.x = 1.f / (wv0 + EPSV); rw.y = 1.f / (wv1 + EPSV);
        rw.z = 1.f / (wv2 + EPSV); rw.w = 1.f / (wv3 + EPSV);

        float* ob = out + ((size_t)b * 10 + t) * 2048 + (16 * h + rh + rr) * 64;
        float4 o0, o1;
        o0.x = acc[0] * rw.x; o0.y = acc[1] * rw.y; o0.z = acc[2] * rw.z; o0.w = acc[3] * rw.w;
        o1.x = acc[4] * rw.x; o1.y = acc[5] * rw.y; o1.z = acc[6] * rw.z; o1.w = acc[7] * rw.w;
        *(float4*)&ob[jj]      = o0;
        *(float4*)&ob[64 + jj] = o1;
    }
}

extern "C" void kernel_launch(void* const* d_in, const int* in_sizes, int n_in,
                              void* d_out, int out_size, void* d_ws, size_t ws_size,
                              hipStream_t stream) {
    const float* feats = (const float*)d_in[0];
    const float* sim   = (const float*)d_in[1];
    k_fused<<<512, 512, 0, stream>>>(feats, sim, (float*)d_out);
}